// Round 8
// baseline (727.373 us; speedup 1.0000x reference)
//
#include <hip/hip_runtime.h>
#include <math.h>

#define L_SEQ   1024
#define DMODEL  2048
#define DINNER  4096
#define DSTATE  16
#define DTRANK  128
#define N_XZ    (2 * DINNER)            // 8192
#define N_XP    (DTRANK + 2 * DSTATE)   // 160
#define EPS_F   1e-5f
#define NCHUNK  32
#define TCH     32
#define SK_XP   16                      // split-K for xdbc GEMM
#define MGRID   512                     // mega grid: 2 blocks/CU x 256 CU, all resident

using bf16x8 = __attribute__((ext_vector_type(8))) short;
using f32x4  = __attribute__((ext_vector_type(4))) float;

__device__ __forceinline__ float silu_f(float v) {
    return v * (1.0f / (1.0f + __expf(-v)));
}
__device__ __forceinline__ float softplus_f(float v) {
    return (v > 15.0f) ? v : log1pf(__expf(v));
}
__device__ __forceinline__ unsigned short f2bf(float f) {
    unsigned b = __float_as_uint(f);
    return (unsigned short)((b + 0x7FFFu + ((b >> 16) & 1u)) >> 16);
}
__device__ __forceinline__ float bf2f(unsigned short u) {
    return __uint_as_float((unsigned)u << 16);
}

#define GLOAD_LDS(gp, lp) \
    __builtin_amdgcn_global_load_lds((const __attribute__((address_space(1))) void*)(gp), \
                                     (__attribute__((address_space(3))) void*)(lp), 16, 0, 0)

// Device-scope grid barrier. SAFE ONLY because grid == MGRID and
// __launch_bounds__(256,2) guarantees 2 blocks/CU co-residency on 256 CUs.
__device__ __forceinline__ void gbar(unsigned* cnt, int idx, unsigned total) {
    __syncthreads();
    if (threadIdx.x == 0) {
        __threadfence();                       // release: drain my stores to device scope
        atomicAdd(&cnt[idx], 1u);
        while (__hip_atomic_load(&cnt[idx], __ATOMIC_RELAXED, __HIP_MEMORY_SCOPE_AGENT) < total)
            __builtin_amdgcn_s_sleep(16);
        __threadfence();                       // acquire: invalidate stale cached lines
    }
    __syncthreads();
}

// ================= mega-prep: all weight transposes + RMSNorm + barrier-counter zero ====
__device__ __forceinline__ void transpose_body(const float* __restrict__ W,
                                               unsigned short* __restrict__ BT,
                                               int K, int N, int bx, int by,
                                               unsigned short (*Tl)[72]) {
    const int k0 = by * 64, n0 = bx * 32;
    const int kr = threadIdx.x >> 3;
    const int nc = (threadIdx.x & 7) * 4;
    float4 v0 = *(const float4*)&W[(size_t)(k0 + kr) * N + n0 + nc];
    float4 v1 = *(const float4*)&W[(size_t)(k0 + kr + 32) * N + n0 + nc];
    Tl[nc + 0][kr] = f2bf(v0.x); Tl[nc + 1][kr] = f2bf(v0.y);
    Tl[nc + 2][kr] = f2bf(v0.z); Tl[nc + 3][kr] = f2bf(v0.w);
    Tl[nc + 0][kr + 32] = f2bf(v1.x); Tl[nc + 1][kr + 32] = f2bf(v1.y);
    Tl[nc + 2][kr + 32] = f2bf(v1.z); Tl[nc + 3][kr + 32] = f2bf(v1.w);
    __syncthreads();
    const int n = threadIdx.x >> 3;
    const int k8 = (threadIdx.x & 7) * 8;
    *(bf16x8*)&BT[(size_t)(n0 + n) * K + k0 + k8] = *(const bf16x8*)&Tl[n][k8];
}

__global__ __launch_bounds__(256) void prep_kernel(const float* __restrict__ W_in,
                                                   const float* __restrict__ W_xp,
                                                   const float* __restrict__ W_dt,
                                                   const float* __restrict__ W_out,
                                                   const float* __restrict__ x,
                                                   const float* __restrict__ wn,
                                                   unsigned short* __restrict__ BT_in,
                                                   unsigned short* __restrict__ BTxp,
                                                   unsigned short* __restrict__ BTdt,
                                                   unsigned short* __restrict__ BT_out,
                                                   unsigned short* __restrict__ xn_bf,
                                                   unsigned* __restrict__ barcnt) {
    __shared__ unsigned short Tl[32][72];
    __shared__ float red[4];
    int b = blockIdx.x;
    if (b == 0 && threadIdx.x < 16) barcnt[threadIdx.x] = 0;   // zero barrier counters
    if (b < 8192) {                       // W_in: K=2048, N=8192
        transpose_body(W_in, BT_in, DMODEL, N_XZ, b % 256, b / 256, Tl);
    } else if (b < 12288) {               // W_out: K=4096, N=2048
        b -= 8192;
        transpose_body(W_out, BT_out, DINNER, DMODEL, b % 64, b / 64, Tl);
    } else if (b < 12608) {               // W_xp: K=4096, N=160
        b -= 12288;
        transpose_body(W_xp, BTxp, DINNER, N_XP, b % 5, b / 5, Tl);
    } else if (b < 12864) {               // W_dt: K=128, N=4096
        b -= 12608;
        transpose_body(W_dt, BTdt, DTRANK, DINNER, b % 128, b / 128, Tl);
    } else {                              // RMSNorm rows 0..1023
        const int row = b - 12864;
        const float4* xr = (const float4*)(x + (size_t)row * DMODEL);
        float ss = 0.f;
        float4 v0 = xr[threadIdx.x];
        float4 v1 = xr[threadIdx.x + 256];
        ss += v0.x*v0.x + v0.y*v0.y + v0.z*v0.z + v0.w*v0.w;
        ss += v1.x*v1.x + v1.y*v1.y + v1.z*v1.z + v1.w*v1.w;
        #pragma unroll
        for (int o = 32; o > 0; o >>= 1) ss += __shfl_down(ss, o);
        const int lane = threadIdx.x & 63, wv = threadIdx.x >> 6;
        if (lane == 0) red[wv] = ss;
        __syncthreads();
        if (threadIdx.x == 0) {
            float t = red[0] + red[1] + red[2] + red[3];
            red[0] = rsqrtf(t / (float)DMODEL + EPS_F);
        }
        __syncthreads();
        const float scale = red[0];
        const float4* wr = (const float4*)wn;
        float4 w0 = wr[threadIdx.x];
        float4 w1 = wr[threadIdx.x + 256];
        ushort4 o0, o1;
        o0.x = f2bf(v0.x * scale * w0.x); o0.y = f2bf(v0.y * scale * w0.y);
        o0.z = f2bf(v0.z * scale * w0.z); o0.w = f2bf(v0.w * scale * w0.w);
        o1.x = f2bf(v1.x * scale * w1.x); o1.y = f2bf(v1.y * scale * w1.y);
        o1.z = f2bf(v1.z * scale * w1.z); o1.w = f2bf(v1.w * scale * w1.w);
        unsigned short* outr = xn_bf + (size_t)row * DMODEL;
        *(ushort4*)&outr[threadIdx.x * 4] = o0;
        *(ushort4*)&outr[1024 + threadIdx.x * 4] = o1;
    }
}

// ================= standalone xz GEMM (R7 measured config: 64x128, BK=64) =================
template <int BM, int BN, int KC>
__global__ __launch_bounds__(256) void gemm_mfma_kernel(const unsigned short* __restrict__ A,
                                                        const unsigned short* __restrict__ BT,
                                                        unsigned short* __restrict__ C,
                                                        int K, int ldc) {
    constexpr int MT = BM / 32;
    constexpr int NT = BN / 32;
    __shared__ __align__(16) unsigned short Al[KC * BM * 32];
    __shared__ __align__(16) unsigned short Bl[KC * BN * 32];
    const int tid = threadIdx.x;
    const int lane = tid & 63, wave = tid >> 6;
    const int wm = wave >> 1, wn = wave & 1;
    const int bm = blockIdx.y * BM, bn = blockIdx.x * BN;
    const int sr = lane >> 2;
    const int sk = (((lane & 3) ^ ((sr >> 1) & 3))) * 8;
    const int fr = lane & 15;
    const int fq = lane >> 4;
    const int fsw = (fq ^ ((fr >> 1) & 3)) * 8;

    f32x4 acc[MT][NT];
    #pragma unroll
    for (int i = 0; i < MT; ++i)
        #pragma unroll
        for (int j = 0; j < NT; ++j)
            acc[i][j] = (f32x4){0.f, 0.f, 0.f, 0.f};

    for (int k0 = 0; k0 < K; k0 += 32 * KC) {
        #pragma unroll
        for (int p = 0; p < KC; ++p) {
            #pragma unroll
            for (int is = wave; is < BM / 16; is += 4)
                GLOAD_LDS(&A[(size_t)(bm + is * 16 + sr) * K + k0 + p * 32 + sk],
                          &Al[p * BM * 32 + is * 512]);
            #pragma unroll
            for (int is = wave; is < BN / 16; is += 4)
                GLOAD_LDS(&BT[(size_t)(bn + is * 16 + sr) * K + k0 + p * 32 + sk],
                          &Bl[p * BN * 32 + is * 512]);
        }
        __syncthreads();
        #pragma unroll
        for (int p = 0; p < KC; ++p) {
            bf16x8 af[MT], bfr[NT];
            #pragma unroll
            for (int i = 0; i < MT; ++i)
                af[i] = *(const bf16x8*)&Al[p * BM * 32 + (wm * (BM / 2) + i * 16 + fr) * 32 + fsw];
            #pragma unroll
            for (int j = 0; j < NT; ++j)
                bfr[j] = *(const bf16x8*)&Bl[p * BN * 32 + (wn * (BN / 2) + j * 16 + fr) * 32 + fsw];
            #pragma unroll
            for (int i = 0; i < MT; ++i)
                #pragma unroll
                for (int j = 0; j < NT; ++j)
                    acc[i][j] = __builtin_amdgcn_mfma_f32_16x16x32_bf16(af[i], bfr[j], acc[i][j], 0, 0, 0);
        }
        __syncthreads();
    }

    #pragma unroll
    for (int i = 0; i < MT; ++i) {
        const int row = bm + wm * (BM / 2) + i * 16 + fq * 4;
        #pragma unroll
        for (int j = 0; j < NT; ++j) {
            const int col = bn + wn * (BN / 2) + j * 16 + fr;
            #pragma unroll
            for (int r = 0; r < 4; ++r)
                C[(size_t)(row + r) * ldc + col] = f2bf(acc[i][j][r]);
        }
    }
}

// ================= 64x64 GEMM tile (inside mega kernel) =================
// OUTM 1: bf16 softplus(v+aux[col])  OUTM 2: fp32 plain  OUTM 3: fp32 v+aux[row*ldc+col]
template <int OUTM>
__device__ __forceinline__ void gemm_tile64(const unsigned short* A,
                                            const unsigned short* BT,
                                            void* Cv,
                                            int K, int Kc, int koff,
                                            int ldc, int Ncols,
                                            int bm, int bn,
                                            const float* aux,
                                            unsigned short (&Al)[2048],
                                            unsigned short (&Bl)[2048]) {
    const int tid = threadIdx.x;
    const int lane = tid & 63, wave = tid >> 6;
    const int wm = wave >> 1, wn = wave & 1;
    const int sr = lane >> 2;
    const int sk = (((lane & 3) ^ ((sr >> 1) & 3))) * 8;
    const int fr = lane & 15;
    const int fq = lane >> 4;
    const int fsw = (fq ^ ((fr >> 1) & 3)) * 8;

    f32x4 acc[2][2];
    #pragma unroll
    for (int i = 0; i < 2; ++i)
        #pragma unroll
        for (int j = 0; j < 2; ++j)
            acc[i][j] = (f32x4){0.f, 0.f, 0.f, 0.f};

    for (int k0 = 0; k0 < Kc; k0 += 32) {
        GLOAD_LDS(&A[(size_t)(bm + wave * 16 + sr) * K + koff + k0 + sk], &Al[wave * 512]);
        GLOAD_LDS(&BT[(size_t)(bn + wave * 16 + sr) * K + koff + k0 + sk], &Bl[wave * 512]);
        __syncthreads();
        bf16x8 af[2], bfr[2];
        #pragma unroll
        for (int i = 0; i < 2; ++i)
            af[i] = *(const bf16x8*)&Al[(wm * 32 + i * 16 + fr) * 32 + fsw];
        #pragma unroll
        for (int j = 0; j < 2; ++j)
            bfr[j] = *(const bf16x8*)&Bl[(wn * 32 + j * 16 + fr) * 32 + fsw];
        #pragma unroll
        for (int i = 0; i < 2; ++i)
            #pragma unroll
            for (int j = 0; j < 2; ++j)
                acc[i][j] = __builtin_amdgcn_mfma_f32_16x16x32_bf16(af[i], bfr[j], acc[i][j], 0, 0, 0);
        __syncthreads();
    }

    #pragma unroll
    for (int i = 0; i < 2; ++i) {
        const int row = bm + wm * 32 + i * 16 + fq * 4;
        #pragma unroll
        for (int j = 0; j < 2; ++j) {
            const int col = bn + wn * 32 + j * 16 + fr;
            if (col < Ncols) {
                #pragma unroll
                for (int r = 0; r < 4; ++r) {
                    float v = acc[i][j][r];
                    if (OUTM == 1) {
                        ((unsigned short*)Cv)[(size_t)(row + r) * ldc + col] =
                            f2bf(softplus_f(v + aux[col]));
                    } else if (OUTM == 2) {
                        ((float*)Cv)[(size_t)(row + r) * ldc + col] = v;
                    } else {
                        ((float*)Cv)[(size_t)(row + r) * ldc + col] =
                            v + aux[(size_t)(row + r) * ldc + col];
                    }
                }
            }
        }
    }
}

// ================= scan bodies =================
__device__ __forceinline__ void scan1_body(int dblk, int c,
                                           const unsigned short* delta_bf,
                                           const unsigned short* xs_bf,
                                           const float* xdbc,
                                           const float* A_log,
                                           float* S, float* sumdl,
                                           float (&BCs)[TCH][32]) {
    const int d = dblk * 256 + threadIdx.x;
    const int t0 = c * TCH;
    {
        const int tt = threadIdx.x >> 3, q = threadIdx.x & 7;
        *(float4*)&BCs[tt][q * 4] =
            *(const float4*)&xdbc[(size_t)(t0 + tt) * N_XP + DTRANK + q * 4];
    }
    __syncthreads();
    float Aa[16];
    #pragma unroll
    for (int n = 0; n < 16; ++n) Aa[n] = -__expf(A_log[d * 16 + n]);
    float h[16];
    #pragma unroll
    for (int n = 0; n < 16; ++n) h[n] = 0.f;
    float sd = 0.f;
    for (int t = 0; t < TCH; ++t) {
        const float dl = bf2f(delta_bf[(size_t)(t0 + t) * DINNER + d]);
        const float u  = bf2f(xs_bf[(size_t)(t0 + t) * DINNER + d]);
        sd += dl;
        const float du = dl * u;
        #pragma unroll
        for (int n = 0; n < 16; ++n)
            h[n] = fmaf(h[n], __expf(dl * Aa[n]), du * BCs[t][n]);
    }
    float* Sp = &S[((size_t)c * DINNER + d) * 16];
    #pragma unroll
    for (int n = 0; n < 16; n += 4)
        *(float4*)&Sp[n] = make_float4(h[n], h[n + 1], h[n + 2], h[n + 3]);
    sumdl[c * DINNER + d] = sd;
    __syncthreads();
}

__device__ __forceinline__ void scan3_body(int dblk, int c,
                                           const unsigned short* delta_bf,
                                           const unsigned short* xs_bf,
                                           const float* xdbc,
                                           const unsigned short* xz_bf,
                                           const float* A_log,
                                           const float* Dp,
                                           const float* h0,
                                           unsigned short* yg_bf,
                                           float (&BCs)[TCH][32]) {
    const int d = dblk * 256 + threadIdx.x;
    const int t0 = c * TCH;
    {
        const int tt = threadIdx.x >> 3, q = threadIdx.x & 7;
        *(float4*)&BCs[tt][q * 4] =
            *(const float4*)&xdbc[(size_t)(t0 + tt) * N_XP + DTRANK + q * 4];
    }
    __syncthreads();
    float Aa[16];
    #pragma unroll
    for (int n = 0; n < 16; ++n) Aa[n] = -__expf(A_log[d * 16 + n]);
    float h[16];
    const float* h0p = &h0[(size_t)c * (DINNER * 16) + d * 16];
    #pragma unroll
    for (int n = 0; n < 16; n += 4) {
        float4 v = *(const float4*)&h0p[n];
        h[n] = v.x; h[n + 1] = v.y; h[n + 2] = v.z; h[n + 3] = v.w;
    }
    const float Dd = Dp[d];
    for (int t = 0; t < TCH; ++t) {
        const float dl = bf2f(delta_bf[(size_t)(t0 + t) * DINNER + d]);
        const float u  = bf2f(xs_bf[(size_t)(t0 + t) * DINNER + d]);
        const float du = dl * u;
        float y = 0.f;
        #pragma unroll
        for (int n = 0; n < 16; ++n) {
            h[n] = fmaf(h[n], __expf(dl * Aa[n]), du * BCs[t][n]);
            y = fmaf(h[n], BCs[t][16 + n], y);
        }
        const float res = bf2f(xz_bf[(size_t)(t0 + t) * N_XZ + DINNER + d]);
        yg_bf[(size_t)(t0 + t) * DINNER + d] = f2bf((y + u * Dd) * silu_f(res));
    }
    __syncthreads();
}

// ================= mega kernel: conv -> xdbc -> reduce -> delta -> scan x3 -> out ========
// 512 blocks, 2/CU, all co-resident; spin barriers between phases.
__global__ __launch_bounds__(256, 2) void mega_kernel(
    const unsigned short* __restrict__ xz_bf, const float* __restrict__ cw,
    const float* __restrict__ cb, unsigned short* __restrict__ xs_bf,
    const unsigned short* __restrict__ BTxp, float* __restrict__ part,
    float* __restrict__ xdbc, unsigned short* __restrict__ xdbc_dt,
    const unsigned short* __restrict__ BTdt, const float* __restrict__ b_dt,
    unsigned short* __restrict__ delta_bf,
    const float* __restrict__ A_log, const float* __restrict__ Dp,
    float* __restrict__ S, float* __restrict__ sumdl, float* __restrict__ h0,
    unsigned short* __restrict__ yg_bf,
    const unsigned short* __restrict__ BT_out, const float* __restrict__ x,
    float* __restrict__ out, unsigned* __restrict__ barcnt) {
    __shared__ __align__(16) unsigned short Al[2048];
    __shared__ __align__(16) unsigned short Bl[2048];
    __shared__ float BCs[TCH][32];
    const int bid = blockIdx.x;
    const int tid = threadIdx.x;

    // P0: depthwise causal conv (k=4) + SiLU -> xs_bf
    for (int idx = bid * 256 + tid; idx < L_SEQ * DINNER; idx += MGRID * 256) {
        const int t = idx >> 12;
        const int c = idx & (DINNER - 1);
        float acc = cb[c];
        #pragma unroll
        for (int k = 0; k < 4; ++k) {
            const int tt = t + k - 3;
            if (tt >= 0) acc = fmaf(bf2f(xz_bf[(size_t)tt * N_XZ + c]), cw[k * DINNER + c], acc);
        }
        xs_bf[idx] = f2bf(silu_f(acc));
    }
    gbar(barcnt, 0, MGRID);

    // P1: xdbc = xs @ W_xp, split-K x16 -> part (768 tiles)
    for (int tb = bid; tb < 3 * 16 * SK_XP; tb += MGRID) {
        const int bx = tb % 3, by = (tb / 3) & 15, bz = tb / 48;
        gemm_tile64<2>(xs_bf, BTxp, part + (size_t)bz * (L_SEQ * N_XP),
                       DINNER, DINNER / SK_XP, bz * (DINNER / SK_XP),
                       N_XP, N_XP, by * 64, bx * 64, nullptr, Al, Bl);
    }
    gbar(barcnt, 1, MGRID);

    // P2: reduce split-K partials -> xdbc fp32 + xdbc_dt bf16
    for (int i = bid * 256 + tid; i < L_SEQ * N_XP; i += MGRID * 256) {
        float s = 0.f;
        #pragma unroll
        for (int z = 0; z < SK_XP; ++z) s += part[(size_t)z * (L_SEQ * N_XP) + i];
        xdbc[i] = s;
        const int col = i % N_XP;
        if (col < DTRANK) xdbc_dt[(i / N_XP) * DTRANK + col] = f2bf(s);
    }
    gbar(barcnt, 2, MGRID);

    // P3: delta = softplus(xdbc_dt @ W_dt + b_dt) -> bf16 (1024 tiles)
    for (int tb = bid; tb < 64 * 16; tb += MGRID) {
        const int bx = tb & 63, by = tb >> 6;
        gemm_tile64<1>(xdbc_dt, BTdt, delta_bf, DTRANK, DTRANK, 0,
                       DINNER, DINNER, by * 64, bx * 64, b_dt, Al, Bl);
    }
    gbar(barcnt, 3, MGRID);

    // P4: scan pass 1 (512 tiles, 1 per block)
    {
        const int tb = bid;
        scan1_body(tb & 15, tb >> 4, delta_bf, xs_bf, xdbc, A_log, S, sumdl, BCs);
    }
    gbar(barcnt, 4, MGRID);

    // P5: scan pass 2 (stitch chunk boundaries)
    {
        const int i = bid * 256 + tid;
        if (i < DINNER * DSTATE) {
            const int dd = i >> 4;
            const float A = -__expf(A_log[i]);
            float h = 0.f;
            #pragma unroll
            for (int c = 0; c < NCHUNK; ++c) {
                h0[(size_t)c * (DINNER * 16) + i] = h;
                h = h * __expf(A * sumdl[c * DINNER + dd]) + S[(size_t)c * (DINNER * 16) + i];
            }
        }
    }
    gbar(barcnt, 5, MGRID);

    // P6: scan pass 3 + D-skip + gate -> yg_bf (512 tiles)
    {
        const int tb = bid;
        scan3_body(tb & 15, tb >> 4, delta_bf, xs_bf, xdbc, xz_bf,
                   A_log, Dp, h0, yg_bf, BCs);
    }
    gbar(barcnt, 6, MGRID);

    // P7: out = yg @ W_out + x  (512 tiles of 64x64, 1 per block)
    {
        const int bx = bid & 31, by = bid >> 5;
        gemm_tile64<3>(yg_bf, BT_out, out, DINNER, DINNER, 0,
                       DMODEL, DMODEL, by * 64, bx * 64, x, Al, Bl);
    }
}

extern "C" void kernel_launch(void* const* d_in, const int* in_sizes, int n_in,
                              void* d_out, int out_size, void* d_ws, size_t ws_size,
                              hipStream_t stream) {
    const float* x     = (const float*)d_in[0];
    const float* wn    = (const float*)d_in[1];
    const float* W_in  = (const float*)d_in[2];
    const float* cw    = (const float*)d_in[3];
    const float* cb    = (const float*)d_in[4];
    const float* W_xp  = (const float*)d_in[5];
    const float* W_dt  = (const float*)d_in[6];
    const float* b_dt  = (const float*)d_in[7];
    const float* A_log = (const float*)d_in[8];
    const float* Dp    = (const float*)d_in[9];
    const float* W_out = (const float*)d_in[10];
    float* out = (float*)d_out;

    float* ws = (float*)d_ws;                                     // offsets in floats
    unsigned short* xz_bf    = (unsigned short*)ws;               // [0, 4194304)
    unsigned short* xs_bf    = (unsigned short*)(ws + 4194304);
    unsigned short* yg_bf    = (unsigned short*)(ws + 6291456);
    unsigned short* delta_bf = (unsigned short*)(ws + 8388608);
    float*          part     = ws + 10485760;                     // 2,621,440 f
    float*          S        = ws + 13107200;                     // 2,097,152 f
    float*          sumdl    = ws + 15204352;                     //   131,072 f
    float*          h0       = ws + 15335424;                     // 2,097,152 f
    float*          xdbc     = ws + 17432576;                     //   163,840 f
    unsigned short* xn_bf    = (unsigned short*)(ws + 17596416);  // 2,097,152 sh
    unsigned short* BTxp     = (unsigned short*)(ws + 18644992);  //   655,360 sh
    unsigned short* BTdt     = (unsigned short*)(ws + 18972672);  //   524,288 sh
    unsigned short* xdbc_dt  = (unsigned short*)(ws + 19234816);  //   131,072 sh
    unsigned short* BT_in    = (unsigned short*)(ws + 19300352);  // 16,777,216 sh
    unsigned short* BT_out   = (unsigned short*)(ws + 27688960);  //  8,388,608 sh
    unsigned*       barcnt   = (unsigned*)(ws + 31883264);        //        16 u
    // total: ~127.5 MB

    // 1. prep: 4 transposes + RMSNorm + barrier-counter zero
    prep_kernel<<<13888, 256, 0, stream>>>(W_in, W_xp, W_dt, W_out, x, wn,
                                           BT_in, BTxp, BTdt, BT_out, xn_bf, barcnt);
    // 2. xz = xn @ W_in -> bf16  (64x128 tile, 1024 blocks, BK=64)
    gemm_mfma_kernel<64, 128, 2><<<dim3(N_XZ / 128, L_SEQ / 64), 256, 0, stream>>>(
        xn_bf, BT_in, xz_bf, DMODEL, N_XZ);
    // 3. mega: conv -> xdbc -> reduce -> delta -> scan x3 -> out  (512 blocks, resident)
    mega_kernel<<<MGRID, 256, 0, stream>>>(
        xz_bf, cw, cb, xs_bf,
        BTxp, part, xdbc, xdbc_dt,
        BTdt, b_dt, delta_bf,
        A_log, Dp, S, sumdl, h0, yg_bf,
        BT_out, x, out, barcnt);
}